// Round 2
// baseline (1156.787 us; speedup 1.0000x reference)
//
#include <hip/hip_runtime.h>

// NAVAR dims (fixed by the problem)
#define T_LEN   2048
#define BATCH   8
#define HIDDEN  16
#define KSZ     4
#define NVAR    12
#define NGROUPS 96      // ND*NS*NV = 2*4*12
#define TILE_OUT 232    // outputs per block tile
#define BUF     256     // TILE_OUT + HALO
#define HALO    24      // 3*(1+1+2+4) receptive-field halo
#define NTILES  9       // ceil(2048/232)

// ---------------------------------------------------------------------------
// Main kernel: one block per (batch, group, time-tile). Computes the whole
// 4-conv stack for 256 positions in LDS, writes contributions only.
// Single in-place LDS layer buffer (17 KB) -> 8 blocks/CU (100% occupancy).
// In-place safety: layer li reads hb positions >= minP(prev layer) before the
// first barrier; writes positions >= minP(li) after it. Stale positions are
// never read by construction of minP.
// ---------------------------------------------------------------------------
__global__ __launch_bounds__(256, 8) void navar_main(
        const float* __restrict__ x,
        const float* __restrict__ w_in,  const float* __restrict__ b_in,
        const float* __restrict__ w_h,   const float* __restrict__ b_h,
        const float* __restrict__ w_out, const float* __restrict__ b_out,
        float* __restrict__ contrib) {
    __shared__ float xs[BUF];
    __shared__ float hb[HIDDEN][BUF];   // single in-place layer buffer, 16 KB

    const int p    = threadIdx.x;          // position within tile window
    const int tile = blockIdx.x % NTILES;
    const int sg   = blockIdx.x / NTILES;  // (batch, group) stream
    const int b    = sg / NGROUPS;
    const int g    = sg % NGROUPS;
    const int tg   = tile * TILE_OUT + p - HALO;   // global time

    // ---- stage x window (causal zero-pad at tg<0, clamp at end) ----
    float xv = 0.f;
    if (tg >= 0 && tg < T_LEN) xv = x[(size_t)(b * NGROUPS + g) * T_LEN + tg];
    xs[p] = xv;
    __syncthreads();

    // ---- input conv: 1 -> 16, dil 1, ReLU (reads xs, writes hb: no hazard) ----
    if (p >= 3) {
        const float t0 = xs[p-3], t1 = xs[p-2], t2 = xs[p-1], t3 = xs[p];
        const float* w  = w_in + g * HIDDEN * KSZ;   // block-uniform -> s_load
        const float* bb = b_in + g * HIDDEN;
        #pragma unroll
        for (int o = 0; o < HIDDEN; ++o) {
            float acc = bb[o];
            acc += w[o*4+0]*t0; acc += w[o*4+1]*t1;
            acc += w[o*4+2]*t2; acc += w[o*4+3]*t3;
            // per-layer causal padding: layer outputs at tg<0 are zeros
            hb[o][p] = (tg >= 0) ? fmaxf(acc, 0.f) : 0.f;
        }
    }
    __syncthreads();

    // ---- 3 dilated hidden blocks: 16 -> 16, dil 1,2,4, ReLU (in-place) ----
    #pragma unroll
    for (int li = 0; li < 3; ++li) {
        const int d    = 1 << li;
        const int minP = (li == 0) ? 6 : (li == 1 ? 12 : 24);
        float acc[HIDDEN];
        if (p >= minP) {
            // preload all 64 taps into VGPRs (stride-1 LDS, conflict-free)
            float tp[HIDDEN][KSZ];
            #pragma unroll
            for (int i = 0; i < HIDDEN; ++i) {
                tp[i][0] = hb[i][p - 3*d];
                tp[i][1] = hb[i][p - 2*d];
                tp[i][2] = hb[i][p - 1*d];
                tp[i][3] = hb[i][p];
            }
            // weights block-uniform; contiguous 64 floats per output channel
            const float* w  = w_h + (size_t)(li * NGROUPS + g) * (HIDDEN * HIDDEN * KSZ);
            const float* bb = b_h + li * NGROUPS * HIDDEN + g * HIDDEN;
            #pragma unroll
            for (int o = 0; o < HIDDEN; ++o) {
                float a = bb[o];
                const float* wo = w + o * (HIDDEN * KSZ);
                #pragma unroll
                for (int i = 0; i < HIDDEN; ++i) {
                    a += wo[i*4+0]*tp[i][0];
                    a += wo[i*4+1]*tp[i][1];
                    a += wo[i*4+2]*tp[i][2];
                    a += wo[i*4+3]*tp[i][3];
                }
                acc[o] = (tg >= 0) ? fmaxf(a, 0.f) : 0.f;
            }
        }
        __syncthreads();            // all reads done before any write
        if (p >= minP) {
            #pragma unroll
            for (int o = 0; o < HIDDEN; ++o) hb[o][p] = acc[o];
        }
        __syncthreads();            // writes visible before next layer reads
    }

    // ---- 1x1 output conv 16 -> 12, write contributions (coalesced in t) ----
    if (p >= HALO && tg < T_LEN) {     // p>=24 => tg>=0 automatically
        float h[HIDDEN];
        #pragma unroll
        for (int i = 0; i < HIDDEN; ++i) h[i] = hb[i][p];
        const int gds  = g / NVAR;     // (dataset,sample) index 0..7
        const int srcv = g % NVAR;     // source variable
        const float* w  = w_out + g * NVAR * HIDDEN;
        const float* bb = b_out + g * NVAR;
        const size_t conBase  = (((size_t)b * NGROUPS + gds * NVAR) * NVAR + srcv) * T_LEN + tg;
        #pragma unroll
        for (int v = 0; v < NVAR; ++v) {
            float acc = bb[v];
            #pragma unroll
            for (int i = 0; i < HIDDEN; ++i) acc += w[v*HIDDEN + i] * h[i];
            // contributions[b, d, s, dst=v, src=srcv, t]
            contrib[conBase + (size_t)v * NVAR * T_LEN] = acc;
        }
    }
}

// ---------------------------------------------------------------------------
// prediction[b,ds,v,t] = biases[ds,v] + sum_src contrib[b,ds,v,src,t]
// Flat element e = G*T_LEN + t with G = b*96 + ds*12 + v. Each of the 12
// strided reads is lane-coalesced in t; contrib is L2/L3-warm from navar_main.
// ---------------------------------------------------------------------------
__global__ __launch_bounds__(256) void navar_pred(
        const float* __restrict__ contrib, const float* __restrict__ biases,
        float* __restrict__ pred) {
    const int e = blockIdx.x * 256 + threadIdx.x;   // grid sized exactly
    const int t = e % T_LEN;
    const int G = e / T_LEN;
    const float* c = contrib + (size_t)G * NVAR * T_LEN + t;
    float acc = biases[G % NGROUPS];
    #pragma unroll
    for (int s = 0; s < NVAR; ++s) acc += c[(size_t)s * T_LEN];
    pred[e] = acc;
}

extern "C" void kernel_launch(void* const* d_in, const int* in_sizes, int n_in,
                              void* d_out, int out_size, void* d_ws, size_t ws_size,
                              hipStream_t stream) {
    const float* x      = (const float*)d_in[0];
    const float* w_in   = (const float*)d_in[1];
    const float* b_in   = (const float*)d_in[2];
    const float* w_h    = (const float*)d_in[3];
    const float* b_h    = (const float*)d_in[4];
    const float* w_out  = (const float*)d_in[5];
    const float* b_out  = (const float*)d_in[6];
    const float* biases = (const float*)d_in[7];

    float* pred    = (float*)d_out;                               // 8*96*2048 floats
    float* contrib = pred + (size_t)BATCH * NGROUPS * T_LEN;      // 8*96*12*2048 floats

    // main: one block per (batch, group, tile); writes contrib only
    navar_main<<<BATCH * NGROUPS * NTILES, 256, 0, stream>>>(
        x, w_in, b_in, w_h, b_h, w_out, b_out, contrib);
    // prediction reduction: exactly BATCH*NGROUPS*T_LEN / 256 = 6144 blocks
    navar_pred<<<(BATCH * NGROUPS * T_LEN) / 256, 256, 0, stream>>>(
        contrib, biases, pred);
}

// Round 3
// 636.742 us; speedup vs baseline: 1.8167x; 1.8167x over previous
//
#include <hip/hip_runtime.h>

// NAVAR dims (fixed by the problem)
#define T_LEN   2048
#define BATCH   8
#define HIDDEN  16
#define KSZ     4
#define NVAR    12
#define NGROUPS 96      // ND*NS*NV = 2*4*12
#define TILE_OUT 232    // outputs per block tile
#define BUF     256     // TILE_OUT + HALO
#define HALO    24      // 3*(1+1+2+4) receptive-field halo
#define NTILES  9       // ceil(2048/232)

// ---------------------------------------------------------------------------
// One block per (batch, group, time-tile). Whole 4-conv stack in LDS, writes
// contributions only. Single in-place LDS buffer (17 KB).
// Inner loop is i-outer: 4 taps of channel i feed 16 accumulators ->
// live set ~ acc[16]+4 taps ~ 40 VGPRs, no spill under the (256,6) cap.
// In-place safety: layer li reads positions >= 3*d(prev)+3 (all written by the
// previous layer) before the barrier; writes p >= 6*d after it.
// ---------------------------------------------------------------------------
__global__ __launch_bounds__(256, 6) void navar_main(
        const float* __restrict__ x,
        const float* __restrict__ w_in,  const float* __restrict__ b_in,
        const float* __restrict__ w_h,   const float* __restrict__ b_h,
        const float* __restrict__ w_out, const float* __restrict__ b_out,
        float* __restrict__ contrib) {
    __shared__ float xs[BUF];
    __shared__ float hb[HIDDEN][BUF];   // single in-place layer buffer, 16 KB

    const int p    = threadIdx.x;          // position within tile window
    const int tile = blockIdx.x % NTILES;
    const int sg   = blockIdx.x / NTILES;  // (batch, group) stream
    const int b    = sg / NGROUPS;
    const int g    = sg % NGROUPS;
    const int tg   = tile * TILE_OUT + p - HALO;   // global time

    // ---- stage x window (causal zero-pad at tg<0, clamp at end) ----
    float xv = 0.f;
    if (tg >= 0 && tg < T_LEN) xv = x[(size_t)(b * NGROUPS + g) * T_LEN + tg];
    xs[p] = xv;
    __syncthreads();

    // ---- input conv: 1 -> 16, dil 1, ReLU (reads xs, writes hb: no hazard) ----
    if (p >= 3) {
        const float t0 = xs[p-3], t1 = xs[p-2], t2 = xs[p-1], t3 = xs[p];
        const float* w  = w_in + g * HIDDEN * KSZ;   // block-uniform -> s_load
        const float* bb = b_in + g * HIDDEN;
        #pragma unroll
        for (int o = 0; o < HIDDEN; ++o) {
            float acc = bb[o];
            acc += w[o*4+0]*t0; acc += w[o*4+1]*t1;
            acc += w[o*4+2]*t2; acc += w[o*4+3]*t3;
            // per-layer causal padding: layer outputs at tg<0 are zeros
            hb[o][p] = (tg >= 0) ? fmaxf(acc, 0.f) : 0.f;
        }
    }
    __syncthreads();

    // ---- 3 dilated hidden blocks: 16 -> 16, dil 1,2,4, ReLU (in-place) ----
    #pragma unroll 1                       // keep code size bounded; d is runtime
    for (int li = 0; li < 3; ++li) {
        const int d    = 1 << li;
        const int minP = 6 * d;            // 6, 12, 24
        float acc[HIDDEN];
        if (p >= minP) {
            const float* bb = b_h + li * NGROUPS * HIDDEN + g * HIDDEN;
            #pragma unroll
            for (int o = 0; o < HIDDEN; ++o) acc[o] = bb[o];
            const float* w = w_h + (size_t)(li * NGROUPS + g) * (HIDDEN * HIDDEN * KSZ);
            #pragma unroll
            for (int i = 0; i < HIDDEN; ++i) {
                // 4 taps of input channel i (stride-1 LDS, conflict-free)
                const float t0 = hb[i][p - 3*d];
                const float t1 = hb[i][p - 2*d];
                const float t2 = hb[i][p - 1*d];
                const float t3 = hb[i][p];
                #pragma unroll
                for (int o = 0; o < HIDDEN; ++o) {
                    const float* wo = w + o * (HIDDEN * KSZ) + i * KSZ;  // s_load
                    acc[o] += wo[0]*t0 + wo[1]*t1 + wo[2]*t2 + wo[3]*t3;
                }
            }
        }
        __syncthreads();            // all reads done before any write
        if (p >= minP) {
            #pragma unroll
            for (int o = 0; o < HIDDEN; ++o)
                hb[o][p] = (tg >= 0) ? fmaxf(acc[o], 0.f) : 0.f;
        }
        __syncthreads();            // writes visible before next layer reads
    }

    // ---- 1x1 output conv 16 -> 12, write contributions (coalesced in t) ----
    if (p >= HALO && tg < T_LEN) {     // p>=24 => tg>=0 automatically
        float h[HIDDEN];
        #pragma unroll
        for (int i = 0; i < HIDDEN; ++i) h[i] = hb[i][p];
        const int gds  = g / NVAR;     // (dataset,sample) index 0..7
        const int srcv = g % NVAR;     // source variable
        const float* w  = w_out + g * NVAR * HIDDEN;
        const float* bb = b_out + g * NVAR;
        const size_t conBase  = (((size_t)b * NGROUPS + gds * NVAR) * NVAR + srcv) * T_LEN + tg;
        #pragma unroll
        for (int v = 0; v < NVAR; ++v) {
            float acc = bb[v];
            #pragma unroll
            for (int i = 0; i < HIDDEN; ++i) acc += w[v*HIDDEN + i] * h[i];
            // contributions[b, d, s, dst=v, src=srcv, t]
            contrib[conBase + (size_t)v * NVAR * T_LEN] = acc;
        }
    }
}

// ---------------------------------------------------------------------------
// prediction[b,ds,v,t] = biases[ds,v] + sum_src contrib[b,ds,v,src,t]
// ---------------------------------------------------------------------------
__global__ __launch_bounds__(256) void navar_pred(
        const float* __restrict__ contrib, const float* __restrict__ biases,
        float* __restrict__ pred) {
    const int e = blockIdx.x * 256 + threadIdx.x;   // grid sized exactly
    const int t = e % T_LEN;
    const int G = e / T_LEN;
    const float* c = contrib + (size_t)G * NVAR * T_LEN + t;
    float acc = biases[G % NGROUPS];
    #pragma unroll
    for (int s = 0; s < NVAR; ++s) acc += c[(size_t)s * T_LEN];
    pred[e] = acc;
}

extern "C" void kernel_launch(void* const* d_in, const int* in_sizes, int n_in,
                              void* d_out, int out_size, void* d_ws, size_t ws_size,
                              hipStream_t stream) {
    const float* x      = (const float*)d_in[0];
    const float* w_in   = (const float*)d_in[1];
    const float* b_in   = (const float*)d_in[2];
    const float* w_h    = (const float*)d_in[3];
    const float* b_h    = (const float*)d_in[4];
    const float* w_out  = (const float*)d_in[5];
    const float* b_out  = (const float*)d_in[6];
    const float* biases = (const float*)d_in[7];

    float* pred    = (float*)d_out;                               // 8*96*2048 floats
    float* contrib = pred + (size_t)BATCH * NGROUPS * T_LEN;      // 8*96*12*2048 floats

    // main: one block per (batch, group, tile); writes contrib only
    navar_main<<<BATCH * NGROUPS * NTILES, 256, 0, stream>>>(
        x, w_in, b_in, w_h, b_h, w_out, b_out, contrib);
    // prediction reduction: exactly BATCH*NGROUPS*T_LEN / 256 = 6144 blocks
    navar_pred<<<(BATCH * NGROUPS * T_LEN) / 256, 256, 0, stream>>>(
        contrib, biases, pred);
}

// Round 4
// 398.396 us; speedup vs baseline: 2.9036x; 1.5983x over previous
//
#include <hip/hip_runtime.h>

// NAVAR dims (fixed by the problem)
#define T_LEN   2048
#define BATCH   8
#define HIDDEN  16
#define KSZ     4
#define NVAR    12
#define NGROUPS 96      // ND*NS*NV = 2*4*12
#define TILE_OUT 232    // outputs per block tile
#define BUF     256     // TILE_OUT + HALO
#define HALO    24      // 3*(1+1+2+4) receptive-field halo
#define NTILES  9       // ceil(2048/232)

// ---------------------------------------------------------------------------
// Hidden layer LI with compile-time dilation D: src buffer -> dst buffer.
// i-outer: 4 taps of channel i feed all 16 accumulators. acc[] never crosses
// a barrier (the barrier-crossing-array structure of R2/R3 caused scratch
// spill: 1.5 GB HBM traffic at VGPR=40). Weights are block-uniform -> s_load,
// feeding v_fmac's SGPR operand (scalar pipe runs parallel to VALU).
// ---------------------------------------------------------------------------
template<int LI, int D>
__device__ __forceinline__ void hidden_layer(
        const float (*__restrict__ src)[BUF], float (*__restrict__ dst)[BUF],
        const float* __restrict__ w_h, const float* __restrict__ b_h,
        int p, int tg, int g) {
    if (p >= 6 * D) {                    // minP: 6, 12, 24
        const float* bb = b_h + LI * NGROUPS * HIDDEN + g * HIDDEN;
        float acc[HIDDEN];
        #pragma unroll
        for (int o = 0; o < HIDDEN; ++o) acc[o] = bb[o];
        const float* w = w_h + (size_t)(LI * NGROUPS + g) * (HIDDEN * HIDDEN * KSZ);
        #pragma unroll
        for (int i = 0; i < HIDDEN; ++i) {
            // 4 taps of channel i: stride-1 LDS, compile-time offsets
            const float t0 = src[i][p - 3*D];
            const float t1 = src[i][p - 2*D];
            const float t2 = src[i][p - 1*D];
            const float t3 = src[i][p];
            #pragma unroll
            for (int o = 0; o < HIDDEN; ++o) {
                const float* wo = w + o * (HIDDEN * KSZ) + i * KSZ;  // s_load
                acc[o] += wo[0]*t0 + wo[1]*t1 + wo[2]*t2 + wo[3]*t3;
            }
        }
        #pragma unroll
        for (int o = 0; o < HIDDEN; ++o)
            dst[o][p] = (tg >= 0) ? fmaxf(acc[o], 0.f) : 0.f;  // causal zero-pad
    }
    // in-place safety not needed (ping-pong); tap coverage: layer LI reads
    // src positions >= 6D-3D = 3D = minP(prev layer) -- always valid.
}

// ---------------------------------------------------------------------------
// One block per (batch, group, time-tile). Whole 4-conv stack via ping-pong
// LDS buffers; xs aliased into hb[1] (dead before layer-1 writes it).
// LDS = 2*16*256*4 = 32768 B exactly -> 5 blocks/CU.
// ---------------------------------------------------------------------------
__global__ __launch_bounds__(256, 4) void navar_main(
        const float* __restrict__ x,
        const float* __restrict__ w_in,  const float* __restrict__ b_in,
        const float* __restrict__ w_h,   const float* __restrict__ b_h,
        const float* __restrict__ w_out, const float* __restrict__ b_out,
        float* __restrict__ contrib) {
    __shared__ float hb[2][HIDDEN][BUF];   // ping-pong buffers, 32 KB total
    float* xs = hb[1][0];                  // alias: hb[1] untouched until L1

    const int p    = threadIdx.x;          // position within tile window
    const int tile = blockIdx.x % NTILES;
    const int sg   = blockIdx.x / NTILES;  // (batch, group) stream
    const int b    = sg / NGROUPS;
    const int g    = sg % NGROUPS;
    const int tg   = tile * TILE_OUT + p - HALO;   // global time

    // ---- stage x window (causal zero-pad at tg<0, clamp at end) ----
    float xv = 0.f;
    if (tg >= 0 && tg < T_LEN) xv = x[(size_t)(b * NGROUPS + g) * T_LEN + tg];
    xs[p] = xv;
    __syncthreads();

    // ---- input conv: 1 -> 16, dil 1, ReLU (reads xs in hb[1], writes hb[0]) ----
    if (p >= 3) {
        const float t0 = xs[p-3], t1 = xs[p-2], t2 = xs[p-1], t3 = xs[p];
        const float* w  = w_in + g * HIDDEN * KSZ;   // block-uniform -> s_load
        const float* bb = b_in + g * HIDDEN;
        #pragma unroll
        for (int o = 0; o < HIDDEN; ++o) {
            float acc = bb[o];
            acc += w[o*4+0]*t0; acc += w[o*4+1]*t1;
            acc += w[o*4+2]*t2; acc += w[o*4+3]*t3;
            hb[0][o][p] = (tg >= 0) ? fmaxf(acc, 0.f) : 0.f;
        }
    }
    __syncthreads();

    // ---- 3 dilated hidden blocks (compile-time dilations, ping-pong) ----
    hidden_layer<0, 1>(hb[0], hb[1], w_h, b_h, p, tg, g);   // overwrites xs: ok
    __syncthreads();
    hidden_layer<1, 2>(hb[1], hb[0], w_h, b_h, p, tg, g);
    __syncthreads();
    hidden_layer<2, 4>(hb[0], hb[1], w_h, b_h, p, tg, g);
    __syncthreads();

    // ---- 1x1 output conv 16 -> 12, write contributions (coalesced in t) ----
    if (p >= HALO && tg < T_LEN) {     // p>=24 => tg>=0 automatically
        float h[HIDDEN];
        #pragma unroll
        for (int i = 0; i < HIDDEN; ++i) h[i] = hb[1][i][p];
        const int gds  = g / NVAR;     // (dataset,sample) index 0..7
        const int srcv = g % NVAR;     // source variable
        const float* w  = w_out + g * NVAR * HIDDEN;
        const float* bb = b_out + g * NVAR;
        const size_t conBase = (((size_t)b * NGROUPS + gds * NVAR) * NVAR + srcv) * T_LEN + tg;
        #pragma unroll
        for (int v = 0; v < NVAR; ++v) {
            float acc = bb[v];
            #pragma unroll
            for (int i = 0; i < HIDDEN; ++i) acc += w[v*HIDDEN + i] * h[i];
            // contributions[b, d, s, dst=v, src=srcv, t]
            contrib[conBase + (size_t)v * NVAR * T_LEN] = acc;
        }
    }
}

// ---------------------------------------------------------------------------
// prediction[b,ds,v,t] = biases[ds,v] + sum_src contrib[b,ds,v,src,t]
// float4 per thread: 12 independent 16-B loads (ILP) + one 16-B store.
// ---------------------------------------------------------------------------
__global__ __launch_bounds__(256) void navar_pred(
        const float* __restrict__ contrib, const float* __restrict__ biases,
        float* __restrict__ pred) {
    const int e = (blockIdx.x * 256 + threadIdx.x) * 4;   // grid sized exactly
    const int t = e % T_LEN;
    const int G = e / T_LEN;
    const float4* c = (const float4*)(contrib + (size_t)G * NVAR * T_LEN + t);
    const float bias = biases[G % NGROUPS];
    float4 acc = make_float4(bias, bias, bias, bias);
    #pragma unroll
    for (int s = 0; s < NVAR; ++s) {
        float4 v = c[(size_t)s * (T_LEN / 4)];
        acc.x += v.x; acc.y += v.y; acc.z += v.z; acc.w += v.w;
    }
    *(float4*)(pred + e) = acc;
}

extern "C" void kernel_launch(void* const* d_in, const int* in_sizes, int n_in,
                              void* d_out, int out_size, void* d_ws, size_t ws_size,
                              hipStream_t stream) {
    const float* x      = (const float*)d_in[0];
    const float* w_in   = (const float*)d_in[1];
    const float* b_in   = (const float*)d_in[2];
    const float* w_h    = (const float*)d_in[3];
    const float* b_h    = (const float*)d_in[4];
    const float* w_out  = (const float*)d_in[5];
    const float* b_out  = (const float*)d_in[6];
    const float* biases = (const float*)d_in[7];

    float* pred    = (float*)d_out;                               // 8*96*2048 floats
    float* contrib = pred + (size_t)BATCH * NGROUPS * T_LEN;      // 8*96*12*2048 floats

    // main: one block per (batch, group, tile); writes contrib only
    navar_main<<<BATCH * NGROUPS * NTILES, 256, 0, stream>>>(
        x, w_in, b_in, w_h, b_h, w_out, b_out, contrib);
    // prediction reduction: BATCH*NGROUPS*T_LEN / (256*4) = 1536 blocks
    navar_pred<<<(BATCH * NGROUPS * T_LEN) / (256 * 4), 256, 0, stream>>>(
        contrib, biases, pred);
}

// Round 5
// 194.550 us; speedup vs baseline: 5.9460x; 2.0478x over previous
//
#include <hip/hip_runtime.h>

// NAVAR dims (fixed by the problem)
#define T_LEN   2048
#define BATCH   8
#define HIDDEN  16
#define KSZ     4
#define NVAR    12
#define NGROUPS 96      // ND*NS*NV = 2*4*12
#define TILE_OUT 232    // outputs per block tile
#define BUF     256     // TILE_OUT + HALO
#define HALO    24      // 3*(1+1+2+4) receptive-field halo
#define NTILES  9       // ceil(2048/232)
#define PAD     16      // left pad so dilated taps (pos-12) stay in-bounds
#define ROWLEN  (BUF + PAD)   // 272 bf16 per activation row

typedef __attribute__((ext_vector_type(8))) short bf16x8;   // MFMA A/B frag (m89-verified form)
typedef __attribute__((ext_vector_type(4))) float f32x4;    // MFMA C/D frag

__device__ __forceinline__ unsigned short f2bf(float x) {   // fp32 -> bf16 RNE
    union { float f; unsigned u; } v; v.f = x;
    unsigned r = v.u + 0x7FFFu + ((v.u >> 16) & 1u);
    return (unsigned short)(r >> 16);
}
__device__ __forceinline__ float bf2f(unsigned short h) {
    union { float f; unsigned u; } v; v.u = ((unsigned)h) << 16;
    return v.f;
}

// ---------------------------------------------------------------------------
// Pack w_h (fp32, [3][96][16][64]) -> bf16, SAME element order: packed row o
// is w[o][i][kk] with k = i*4+kk, which is exactly the A-operand k order.
// Runs every call (d_ws is re-poisoned by the harness).
// ---------------------------------------------------------------------------
__global__ __launch_bounds__(256) void navar_pack_w(
        const float* __restrict__ w_h, unsigned short* __restrict__ wp) {
    const int e = blockIdx.x * 256 + threadIdx.x;   // grid sized exactly: 294912
    wp[e] = f2bf(w_h[e]);
}

// ---------------------------------------------------------------------------
// One hidden layer (16->16, kernel 4, dilation D) as MFMA:
//   D[o][n] = sum_k W[o][k] * B[k][n],  k = i*4+kk,  B[k][n] = h[i][pos_n-(3-kk)*D]
// Wave wv covers position tiles tt=4wv..4wv+3 (16 positions each).
// Fragment layouts (verified m89/m91/m120):
//   A[m=lane&15][k=q*8+j]   -> lane's c picks weight row o=c
//   B[k=q*8+j][n=lane&15]   -> 8 ds_read_u16 per frag
//   C/D: col=lane&15=pos, row=q*4+reg=o
// ---------------------------------------------------------------------------
template<int LI, int D>
__device__ __forceinline__ void mfma_layer(
        const unsigned short (*__restrict__ src)[ROWLEN],
        unsigned short (*__restrict__ dst)[ROWLEN],
        const unsigned short* __restrict__ wp, const float* __restrict__ b_h,
        int g, int tile, int wv, int q, int c) {
    // A fragments: row o=c of packed weights, k-halves 0..31 / 32..63
    const unsigned short* wrow =
        wp + (size_t)((LI * NGROUPS + g) * HIDDEN + c) * (HIDDEN * KSZ);
    const bf16x8 a0 = *(const bf16x8*)(wrow + q * 8);        // 16-B aligned
    const bf16x8 a1 = *(const bf16x8*)(wrow + 32 + q * 8);
    const f32x4 bias = *(const f32x4*)(b_h + (LI * NGROUPS + g) * HIDDEN + q * 4);

    #pragma unroll
    for (int tt = 0; tt < 4; ++tt) {
        const int pos = (wv * 4 + tt) * 16 + c;              // window position
        bf16x8 b0, b1;
        #pragma unroll
        for (int j = 0; j < 8; ++j) {
            const int kk  = j & 3;
            const int off = PAD + pos - (3 - kk) * D;        // >= PAD-12 >= 4
            b0[j] = (short)src[q * 2 + (j >> 2)][off];       // i = q*2+(j>>2)
            b1[j] = (short)src[8 + q * 2 + (j >> 2)][off];   // i = 8+q*2+(j>>2)
        }
        f32x4 acc = bias;
        acc = __builtin_amdgcn_mfma_f32_16x16x32_bf16(a0, b0, acc, 0, 0, 0);
        acc = __builtin_amdgcn_mfma_f32_16x16x32_bf16(a1, b1, acc, 0, 0, 0);
        const int tgp = tile * TILE_OUT + pos - HALO;        // causal zero-pad
        #pragma unroll
        for (int r = 0; r < 4; ++r) {
            const float v = (tgp >= 0) ? fmaxf(acc[r], 0.f) : 0.f;
            dst[q * 4 + r][PAD + pos] = f2bf(v);             // o = q*4+r
        }
    }
    // validity chain: layer LI output valid at window p>=6D; its taps reach
    // back 3D -> reads prev-layer positions >= 3D = its validity bound. Garbage
    // at p<6D is written but never consumed by a valid output.
}

// ---------------------------------------------------------------------------
// One block per (batch, group, time-tile). Input conv fp32->bf16, 3 MFMA
// hidden layers (ping-pong bf16 LDS), output conv fp32. LDS = 18432 B.
// ---------------------------------------------------------------------------
__global__ __launch_bounds__(256, 4) void navar_main(
        const float* __restrict__ x,
        const float* __restrict__ w_in,  const float* __restrict__ b_in,
        const unsigned short* __restrict__ wp, const float* __restrict__ b_h,
        const float* __restrict__ w_out, const float* __restrict__ b_out,
        float* __restrict__ contrib) {
    __shared__ float xs[BUF];
    __shared__ unsigned short hbuf[2][HIDDEN][ROWLEN];   // 2 x 8704 B, bf16

    const int p    = threadIdx.x;
    const int tile = blockIdx.x % NTILES;
    const int sg   = blockIdx.x / NTILES;
    const int b    = sg / NGROUPS;
    const int g    = sg % NGROUPS;
    const int tg   = tile * TILE_OUT + p - HALO;

    // ---- stage x window ----
    float xv = 0.f;
    if (tg >= 0 && tg < T_LEN) xv = x[(size_t)(b * NGROUPS + g) * T_LEN + tg];
    xs[p] = xv;
    __syncthreads();

    // ---- input conv 1->16 fp32, store bf16 into hbuf[0] ----
    if (p >= 3) {
        const float t0 = xs[p-3], t1 = xs[p-2], t2 = xs[p-1], t3 = xs[p];
        const float* w  = w_in + g * HIDDEN * KSZ;   // block-uniform -> s_load
        const float* bb = b_in + g * HIDDEN;
        #pragma unroll
        for (int o = 0; o < HIDDEN; ++o) {
            float acc = fmaf(w[o*4+0], t0, bb[o]);
            acc = fmaf(w[o*4+1], t1, acc);
            acc = fmaf(w[o*4+2], t2, acc);
            acc = fmaf(w[o*4+3], t3, acc);
            hbuf[0][o][PAD + p] = (tg >= 0) ? f2bf(fmaxf(acc, 0.f))
                                            : (unsigned short)0;
        }
    }
    __syncthreads();

    // ---- 3 dilated hidden blocks via MFMA (ping-pong) ----
    const int wv = p >> 6, q = (p >> 4) & 3, c = p & 15;
    mfma_layer<0, 1>(hbuf[0], hbuf[1], wp, b_h, g, tile, wv, q, c);
    __syncthreads();
    mfma_layer<1, 2>(hbuf[1], hbuf[0], wp, b_h, g, tile, wv, q, c);
    __syncthreads();
    mfma_layer<2, 4>(hbuf[0], hbuf[1], wp, b_h, g, tile, wv, q, c);
    __syncthreads();

    // ---- 1x1 output conv 16->12 fp32, write contributions ----
    if (p >= HALO && tg < T_LEN) {
        float h[HIDDEN];
        #pragma unroll
        for (int i = 0; i < HIDDEN; ++i) h[i] = bf2f(hbuf[1][i][PAD + p]);
        const int gds  = g / NVAR;
        const int srcv = g % NVAR;
        const float* w  = w_out + g * NVAR * HIDDEN;
        const float* bb = b_out + g * NVAR;
        const size_t conBase =
            (((size_t)b * NGROUPS + gds * NVAR) * NVAR + srcv) * T_LEN + tg;
        #pragma unroll
        for (int v = 0; v < NVAR; ++v) {
            float acc = bb[v];
            #pragma unroll
            for (int i = 0; i < HIDDEN; ++i) acc = fmaf(w[v*HIDDEN + i], h[i], acc);
            contrib[conBase + (size_t)v * NVAR * T_LEN] = acc;
        }
    }
}

// ---------------------------------------------------------------------------
// prediction[b,ds,v,t] = biases[ds,v] + sum_src contrib[b,ds,v,src,t]
// ---------------------------------------------------------------------------
__global__ __launch_bounds__(256) void navar_pred(
        const float* __restrict__ contrib, const float* __restrict__ biases,
        float* __restrict__ pred) {
    const int e = (blockIdx.x * 256 + threadIdx.x) * 4;
    const int t = e % T_LEN;
    const int G = e / T_LEN;
    const float4* c = (const float4*)(contrib + (size_t)G * NVAR * T_LEN + t);
    const float bias = biases[G % NGROUPS];
    float4 acc = make_float4(bias, bias, bias, bias);
    #pragma unroll
    for (int s = 0; s < NVAR; ++s) {
        float4 v = c[(size_t)s * (T_LEN / 4)];
        acc.x += v.x; acc.y += v.y; acc.z += v.z; acc.w += v.w;
    }
    *(float4*)(pred + e) = acc;
}

extern "C" void kernel_launch(void* const* d_in, const int* in_sizes, int n_in,
                              void* d_out, int out_size, void* d_ws, size_t ws_size,
                              hipStream_t stream) {
    const float* x      = (const float*)d_in[0];
    const float* w_in   = (const float*)d_in[1];
    const float* b_in   = (const float*)d_in[2];
    const float* w_h    = (const float*)d_in[3];
    const float* b_h    = (const float*)d_in[4];
    const float* w_out  = (const float*)d_in[5];
    const float* b_out  = (const float*)d_in[6];
    const float* biases = (const float*)d_in[7];

    float* pred    = (float*)d_out;                               // 8*96*2048 floats
    float* contrib = pred + (size_t)BATCH * NGROUPS * T_LEN;      // 8*96*12*2048 floats
    unsigned short* wp = (unsigned short*)d_ws;                   // 294912 bf16

    // pack hidden weights to bf16 (3*96*16*64 = 294912 elements)
    navar_pack_w<<<(3 * NGROUPS * HIDDEN * HIDDEN * KSZ) / 256, 256, 0, stream>>>(
        w_h, wp);
    // main: one block per (batch, group, tile)
    navar_main<<<BATCH * NGROUPS * NTILES, 256, 0, stream>>>(
        x, w_in, b_in, wp, b_h, w_out, b_out, contrib);
    // prediction reduction: BATCH*NGROUPS*T_LEN / (256*4) = 1536 blocks
    navar_pred<<<(BATCH * NGROUPS * T_LEN) / (256 * 4), 256, 0, stream>>>(
        contrib, biases, pred);
}

// Round 6
// 149.116 us; speedup vs baseline: 7.7576x; 1.3047x over previous
//
#include <hip/hip_runtime.h>

// NAVAR dims (fixed by the problem)
#define T_LEN   2048
#define BATCH   8
#define HIDDEN  16
#define KSZ     4
#define NVAR    12
#define NGROUPS 96      // ND*NS*NV = 2*4*12
#define TILE_OUT 232    // outputs per block tile
#define BUF     256     // TILE_OUT + HALO
#define HALO    24      // 3*(1+1+2+4) receptive-field halo
#define NTILES  9       // ceil(2048/232)
#define PAD     16      // left pad rows so dilated taps (pos-12) stay in-bounds
#define NROWS   (BUF + PAD)   // 272 position rows
#define ROWCH   24      // 16 channels + 8 pad (48 B rows: 16-B aligned, ~2-way banks)

#define NWH  (3 * NGROUPS * HIDDEN * HIDDEN * KSZ)   // 294912 hidden weights
#define NWO  (NGROUPS * HIDDEN * 32)                 // 49152 padded out weights

typedef __attribute__((ext_vector_type(8))) short bf16x8;   // MFMA A/B frag
typedef __attribute__((ext_vector_type(4))) float f32x4;    // MFMA C/D frag

__device__ __forceinline__ unsigned short f2bf(float x) {   // fp32 -> bf16 RNE
    union { float f; unsigned u; } v; v.f = x;
    unsigned r = v.u + 0x7FFFu + ((v.u >> 16) & 1u);
    return (unsigned short)(r >> 16);
}

// ---------------------------------------------------------------------------
// Pack weights to bf16 with MFMA-friendly k-order.
// Hidden: wp[row][k'] with k' = kk*16 + i  (tap-major!), row = (l*96+g)*16+o.
//   -> A-frag = contiguous 8 k' ; B-frag = 8 consecutive CHANNELS at ONE tap
//      position => single ds_read_b128 from the transposed activation buffer.
// Out:   wpo[(g*16+m)*32 + k] = w_out[g][m][k] for m<12,k<16 else 0.
// ---------------------------------------------------------------------------
__global__ __launch_bounds__(256) void navar_pack(
        const float* __restrict__ w_h, const float* __restrict__ w_out,
        unsigned short* __restrict__ wp, unsigned short* __restrict__ wpo) {
    const int e = blockIdx.x * 256 + threadIdx.x;   // grid covers NWH+NWO exactly
    if (e < NWH) {
        const int k  = e & 63, row = e >> 6;
        const int kk = k >> 4, i = k & 15;
        wp[e] = f2bf(w_h[(row << 6) + i * 4 + kk]);
    } else {
        const int e2 = e - NWH;
        const int k = e2 & 31, m = (e2 >> 5) & 15, g = e2 >> 9;
        wpo[e2] = (k < 16 && m < 12) ? f2bf(w_out[(g * NVAR + m) * HIDDEN + k])
                                     : (unsigned short)0;
    }
}

// ---------------------------------------------------------------------------
// One hidden layer (16->16, kernel 4, dilation D) as 2 MFMAs per 16-pos tile.
// Logical k' = kk*16 + i. Lane (q=lane>>4, c=lane&15) supplies:
//   A[m=c][k=q*8+j]           (global b128 from packed weights)
//   B[k=q*8+j][n=c]           (LDS  b128: 8 channels, tap row per (q,half))
// and receives D rows o=q*4+r at col pos=c -> ds_write_b64 (4 channels).
// Validity: output valid at pos>=6D reads prev positions >=3D (= prev minP).
// Garbage below that is finite-or-NaN but never feeds a valid output.
// ---------------------------------------------------------------------------
template<int LI, int D>
__device__ __forceinline__ void mfma_layer(
        const unsigned short (*__restrict__ src)[ROWCH],
        unsigned short (*__restrict__ dst)[ROWCH],
        const unsigned short* __restrict__ wp, const float* __restrict__ b_h,
        int g, int tile, int wv, int q, int c) {
    const unsigned short* wrow =
        wp + (size_t)((LI * NGROUPS + g) * HIDDEN + c) * (HIDDEN * KSZ);
    const bf16x8 a0 = *(const bf16x8*)(wrow + q * 8);        // k' = q*8+j
    const bf16x8 a1 = *(const bf16x8*)(wrow + 32 + q * 8);   // k' = 32+q*8+j
    const f32x4 bias = *(const f32x4*)(b_h + (LI * NGROUPS + g) * HIDDEN + q * 4);
    const int ch = (q & 1) * 8;            // channel half this q supplies
    const int d0 = (3 - (q >> 1)) * D;     // tap offset, MFMA#0 (kk = q>>1)
    const int d1 = (1 - (q >> 1)) * D;     // tap offset, MFMA#1 (kk = 2+(q>>1))

    #pragma unroll
    for (int tt = 0; tt < 4; ++tt) {
        const int pos = (wv * 4 + tt) * 16 + c;
        const bf16x8 b0 = *(const bf16x8*)&src[PAD + pos - d0][ch];
        const bf16x8 b1 = *(const bf16x8*)&src[PAD + pos - d1][ch];
        f32x4 acc = bias;
        acc = __builtin_amdgcn_mfma_f32_16x16x32_bf16(a0, b0, acc, 0, 0, 0);
        acc = __builtin_amdgcn_mfma_f32_16x16x32_bf16(a1, b1, acc, 0, 0, 0);
        const int tgp = tile * TILE_OUT + pos - HALO;   // causal zero-pad
        union { unsigned short s[4]; uint2 u; } pk;
        #pragma unroll
        for (int r = 0; r < 4; ++r)
            pk.s[r] = (tgp >= 0) ? f2bf(fmaxf(acc[r], 0.f)) : (unsigned short)0;
        *(uint2*)&dst[PAD + pos][q * 4] = pk.u;         // ds_write_b64
    }
}

// ---------------------------------------------------------------------------
// One block per (batch, group, time-tile). Input conv fp32 (K=4, cheap),
// 3 MFMA hidden layers (ping-pong transposed bf16 LDS), output 1x1 conv as
// ONE MFMA (K=32 with zero-padded A) storing straight to global.
// LDS = 2*272*24*2 = 26112 B -> 6 blocks/CU.
// ---------------------------------------------------------------------------
__global__ __launch_bounds__(256, 6) void navar_main(
        const float* __restrict__ x,
        const float* __restrict__ w_in,  const float* __restrict__ b_in,
        const unsigned short* __restrict__ wp, const float* __restrict__ b_h,
        const unsigned short* __restrict__ wpo, const float* __restrict__ b_out,
        float* __restrict__ contrib) {
    __shared__ unsigned short hb[2][NROWS][ROWCH];   // transposed: [pos][ch]
    float* xs = (float*)&hb[1][0][0];                // alias: hb[1] dead until L1

    const int p    = threadIdx.x;
    const int tile = blockIdx.x % NTILES;
    const int sg   = blockIdx.x / NTILES;
    const int b    = sg / NGROUPS;
    const int g    = sg % NGROUPS;
    const int tg   = tile * TILE_OUT + p - HALO;

    // ---- stage x window ----
    float xv = 0.f;
    if (tg >= 0 && tg < T_LEN) xv = x[(size_t)(b * NGROUPS + g) * T_LEN + tg];
    xs[p] = xv;
    __syncthreads();

    // ---- input conv 1->16 fp32; pack 16 bf16 -> 32 B ds_write_b128 x2 ----
    if (p >= 3) {
        const float t0 = xs[p-3], t1 = xs[p-2], t2 = xs[p-1], t3 = xs[p];
        const float* w  = w_in + g * HIDDEN * KSZ;   // block-uniform -> s_load
        const float* bb = b_in + g * HIDDEN;
        unsigned pk[8];
        #pragma unroll
        for (int o = 0; o < HIDDEN; ++o) {
            float acc = fmaf(w[o*4+0], t0, bb[o]);
            acc = fmaf(w[o*4+1], t1, acc);
            acc = fmaf(w[o*4+2], t2, acc);
            acc = fmaf(w[o*4+3], t3, acc);
            const unsigned short h =
                (tg >= 0) ? f2bf(fmaxf(acc, 0.f)) : (unsigned short)0;
            if (o & 1) pk[o >> 1] |= ((unsigned)h) << 16;
            else       pk[o >> 1] = h;
        }
        uint4* row = (uint4*)&hb[0][PAD + p][0];
        row[0] = make_uint4(pk[0], pk[1], pk[2], pk[3]);
        row[1] = make_uint4(pk[4], pk[5], pk[6], pk[7]);
    }
    __syncthreads();

    // ---- 3 dilated hidden blocks via MFMA (ping-pong) ----
    const int wv = p >> 6, q = (p >> 4) & 3, c = p & 15;
    mfma_layer<0, 1>(hb[0], hb[1], wp, b_h, g, tile, wv, q, c);  // clobbers xs: ok
    __syncthreads();
    mfma_layer<1, 2>(hb[1], hb[0], wp, b_h, g, tile, wv, q, c);
    __syncthreads();
    mfma_layer<2, 4>(hb[0], hb[1], wp, b_h, g, tile, wv, q, c);
    __syncthreads();

    // ---- output 1x1 conv 16->12 as one MFMA; D rows=v, cols=pos ----
    {
        const unsigned short* wrow = wpo + (size_t)(g * HIDDEN + c) * 32;
        const bf16x8 a0 = *(const bf16x8*)(wrow + q * 8);   // zeros for q>=2
        f32x4 bias = {0.f, 0.f, 0.f, 0.f};
        if (q < 3) bias = *(const f32x4*)(b_out + g * NVAR + q * 4);
        const int gds = g / NVAR, srcv = g % NVAR;
        #pragma unroll
        for (int tt = 0; tt < 4; ++tt) {
            const int pos = (wv * 4 + tt) * 16 + c;
            const bf16x8 b0 = *(const bf16x8*)&hb[1][PAD + pos][(q & 1) * 8];
            f32x4 acc = bias;
            acc = __builtin_amdgcn_mfma_f32_16x16x32_bf16(a0, b0, acc, 0, 0, 0);
            const int tgp = tile * TILE_OUT + pos - HALO;
            if (q < 3 && pos >= HALO && tgp < T_LEN) {
                const size_t base =
                    (((size_t)b * NGROUPS + gds * NVAR) * NVAR + srcv) * T_LEN + tgp;
                #pragma unroll
                for (int r = 0; r < 4; ++r)   // v = q*4+r; lanes c -> coalesced tg
                    contrib[base + (size_t)(q * 4 + r) * NVAR * T_LEN] = acc[r];
            }
        }
    }
}

// ---------------------------------------------------------------------------
// prediction[b,ds,v,t] = biases[ds,v] + sum_src contrib[b,ds,v,src,t]
// ---------------------------------------------------------------------------
__global__ __launch_bounds__(256) void navar_pred(
        const float* __restrict__ contrib, const float* __restrict__ biases,
        float* __restrict__ pred) {
    const int e = (blockIdx.x * 256 + threadIdx.x) * 4;
    const int t = e % T_LEN;
    const int G = e / T_LEN;
    const float4* c = (const float4*)(contrib + (size_t)G * NVAR * T_LEN + t);
    const float bias = biases[G % NGROUPS];
    float4 acc = make_float4(bias, bias, bias, bias);
    #pragma unroll
    for (int s = 0; s < NVAR; ++s) {
        float4 v = c[(size_t)s * (T_LEN / 4)];
        acc.x += v.x; acc.y += v.y; acc.z += v.z; acc.w += v.w;
    }
    *(float4*)(pred + e) = acc;
}

extern "C" void kernel_launch(void* const* d_in, const int* in_sizes, int n_in,
                              void* d_out, int out_size, void* d_ws, size_t ws_size,
                              hipStream_t stream) {
    const float* x      = (const float*)d_in[0];
    const float* w_in   = (const float*)d_in[1];
    const float* b_in   = (const float*)d_in[2];
    const float* w_h    = (const float*)d_in[3];
    const float* b_h    = (const float*)d_in[4];
    const float* w_out  = (const float*)d_in[5];
    const float* b_out  = (const float*)d_in[6];
    const float* biases = (const float*)d_in[7];

    float* pred    = (float*)d_out;                               // 8*96*2048 floats
    float* contrib = pred + (size_t)BATCH * NGROUPS * T_LEN;      // 8*96*12*2048 floats
    unsigned short* wp  = (unsigned short*)d_ws;                  // NWH bf16
    unsigned short* wpo = wp + NWH;                               // NWO bf16

    // pack hidden + output weights to bf16 (k-reordered)
    navar_pack<<<(NWH + NWO) / 256, 256, 0, stream>>>(w_h, w_out, wp, wpo);
    // main: one block per (batch, group, tile)
    navar_main<<<BATCH * NGROUPS * NTILES, 256, 0, stream>>>(
        x, w_in, b_in, wp, b_h, wpo, b_out, contrib);
    // prediction reduction: BATCH*NGROUPS*T_LEN / (256*4) = 1536 blocks
    navar_pred<<<(BATCH * NGROUPS * T_LEN) / (256 * 4), 256, 0, stream>>>(
        contrib, biases, pred);
}